// Round 17
// baseline (159.554 us; speedup 1.0000x reference)
//
#include <hip/hip_runtime.h>

typedef _Float16 half2v __attribute__((ext_vector_type(2)));
typedef _Float16 half8v __attribute__((ext_vector_type(8)));
typedef float f32x4 __attribute__((ext_vector_type(4)));
typedef float f32x16 __attribute__((ext_vector_type(16)));
typedef unsigned uint2v __attribute__((ext_vector_type(2)));

__device__ inline half2v cvt_pk(float a, float b) {
    return __builtin_bit_cast(half2v, __builtin_amdgcn_cvt_pkrtz(a, b));
}
__device__ inline half2v pkmax0(half2v x) {
    half2v r;
    asm("v_pk_max_f16 %0, %1, 0" : "=v"(r) : "v"(x));
    return r;
}
__device__ inline unsigned short f16bits(float f) {
    _Float16 h = (_Float16)f;
    return __builtin_bit_cast(unsigned short, h);
}
__device__ inline unsigned packf16(float a, float b) {
    return (unsigned)f16bits(a) | ((unsigned)f16bits(b) << 16);
}
__device__ inline float lo16(unsigned u) {
    return (float)__builtin_bit_cast(_Float16, (unsigned short)(u & 0xffffu));
}
__device__ inline float hi16(unsigned u) {
    return (float)__builtin_bit_cast(_Float16, (unsigned short)(u >> 16));
}

// ---------------------------------------------------------------------------
// K0: src/dst = relu(LN(node @ W^T + b)) -> f16; A1 = src@W1a^T + b1 (f32);
//     B1h = dst@W1b^T (f16). Blocks 0..7 pack w1c/w2 into 32x32x16 MFMA
//     A-fragment order (assumed A layout: row = l&31, k = (l>>5)*8 + e; any
//     k-map error cancels since B is built with the same map).
//     w2 additionally gets the sigma k-permutation derived from the VERIFIED
//     32x32 C layout (col=l&31, row=(r&3)+8*(r>>2)+4*(l>>5)):
//       sigma: k-slot (hi,e) of 16-block b <- h1-dim 16b + 4*hi + (e>>2)*8 + (e&3)
// ---------------------------------------------------------------------------
__global__ __launch_bounds__(256) void proj_kernel(
    const float* __restrict__ node,
    const float* __restrict__ w_src, const float* __restrict__ b_src,
    const float* __restrict__ g_src, const float* __restrict__ be_src,
    const float* __restrict__ w_dst, const float* __restrict__ b_dst,
    const float* __restrict__ g_dst, const float* __restrict__ be_dst,
    const float* __restrict__ w1, const float* __restrict__ b1,
    const float* __restrict__ w2,
    unsigned short* __restrict__ src_f16, unsigned short* __restrict__ dst_f16,
    float* __restrict__ A1, unsigned short* __restrict__ B1h,
    unsigned short* __restrict__ w1c_frag, unsigned short* __restrict__ w2_frag)
{
    __shared__ unsigned sWh[64 * 65];    // W(kind) as packed f16 pairs, stride 65
    __shared__ unsigned sw1h[128 * 33];  // w1[:,koff:koff+64] f16 pairs, stride 33
    __shared__ float snode[4][128];
    __shared__ float sy[4][64];

    const int tid = threadIdx.x;
    const int wloc = tid >> 6;
    const int lane = tid & 63;
    const int gw = blockIdx.x * 4 + wloc;     // 0..2047
    const int row = gw & 1023;
    const int kind = gw >> 10;                // uniform per block

    const float* W  = kind ? w_dst  : w_src;
    const float* Bv = kind ? b_dst  : b_src;
    const float* G  = kind ? g_dst  : g_src;
    const float* BE = kind ? be_dst : be_src;
    const int koff = kind * 64;

    // ---- stage W (64x128) and w1-slice (128x64) as f16 pairs, coalesced ----
    #pragma unroll
    for (int u = 0; u < 16; u++) {
        int w = u * 256 + tid;                // 0..4095
        int r = w >> 6, c2 = w & 63;
        float2 v = *(const float2*)(W + r * 128 + c2 * 2);
        sWh[r * 65 + c2] = packf16(v.x, v.y);
    }
    #pragma unroll
    for (int u = 0; u < 16; u++) {
        int w = u * 256 + tid;                // 0..4095
        int r = w >> 5, c2 = w & 31;
        float2 v = *(const float2*)(w1 + (size_t)r * 192 + koff + c2 * 2);
        sw1h[r * 33 + c2] = packf16(v.x, v.y);
    }
    snode[wloc][lane]      = node[row * 128 + lane];
    snode[wloc][lane + 64] = node[row * 128 + 64 + lane];
    __syncthreads();

    // ---- projection dot: acc = b + node . W[lane,:] ----
    float acc = Bv[lane];
    #pragma unroll 8
    for (int k2 = 0; k2 < 64; k2++) {
        unsigned wp = sWh[lane * 65 + k2];
        float2 nv = *(const float2*)&snode[wloc][2 * k2];
        acc += nv.x * lo16(wp) + nv.y * hi16(wp);
    }

    // LayerNorm over 64 lanes
    float s = acc;
    #pragma unroll
    for (int off = 32; off >= 1; off >>= 1) s += __shfl_xor(s, off);
    float mean = s * (1.0f / 64.0f);
    float d = acc - mean;
    float ss = d * d;
    #pragma unroll
    for (int off = 32; off >= 1; off >>= 1) ss += __shfl_xor(ss, off);
    float rstd = rsqrtf(ss * (1.0f / 64.0f) + 1e-5f);
    float y = fmaxf(d * rstd * G[lane] + BE[lane], 0.0f);

    unsigned short* obf = kind ? dst_f16 : src_f16;
    obf[row * 64 + lane] = f16bits(y);

    sy[wloc][lane] = y;
    __builtin_amdgcn_s_waitcnt(0);   // within-wave LDS RAW

    // ---- A1/B1 projection: a{0,1} = y . w1[m, koff:koff+64] ----
    float a0 = kind ? 0.0f : b1[lane];
    float a1 = kind ? 0.0f : b1[lane + 64];
    #pragma unroll 8
    for (int k2 = 0; k2 < 32; k2++) {
        float2 yv = *(const float2*)&sy[wloc][2 * k2];
        unsigned wa = sw1h[lane * 33 + k2];
        unsigned wb = sw1h[(lane + 64) * 33 + k2];
        a0 += yv.x * lo16(wa) + yv.y * hi16(wa);
        a1 += yv.x * lo16(wb) + yv.y * hi16(wb);
    }
    if (kind == 0) {
        A1[row * 128 + lane] = a0;
        A1[row * 128 + lane + 64] = a1;
    } else {
        B1h[row * 128 + lane] = f16bits(a0);
        B1h[row * 128 + lane + 64] = f16bits(a1);
    }

    // ---- weight packing (blocks 0..7 only), 32x32x16 A-frag order ----
    if (blockIdx.x < 8) {
        int t = blockIdx.x * 256 + threadIdx.x;   // 0..2047
        int which = t >> 10;
        int idx = t & 1023;                       // f*64 + l
        int f = idx >> 6, l = idx & 63;
        int lrow = l & 31, lhi = l >> 5;
        if (which == 0) {
            // W1c A-frag: f = mt*4 + kt (mt<4, kt<4)
            int mt = f >> 2, kt = f & 3;
            #pragma unroll
            for (int e = 0; e < 8; e++)
                w1c_frag[idx * 8 + e] =
                    f16bits(w1[(size_t)(32 * mt + lrow) * 192 + 128 + 16 * kt + 8 * lhi + e]);
        } else {
            // W2 A-frag with sigma: f = mt2*8 + b (mt2<2, b<8)
            int mt2 = f >> 3, b = f & 7;
            #pragma unroll
            for (int e = 0; e < 8; e++) {
                int col = 16 * b + 4 * lhi + (e >> 2) * 8 + (e & 3);
                w2_frag[idx * 8 + e] =
                    f16bits(w2[(size_t)(32 * mt2 + lrow) * 128 + col]);
            }
        }
    }
}

// ---------------------------------------------------------------------------
// K1: pairwise MLP on 32x32x16 MFMA. Chunk = (one i, 32 j) -> 2x fewer weight
// fragment bytes per pair than the 16x16 form at IDENTICAL acc-register cost
// (R16 showed 4-i grouping spills: WRITE 16.4MB). Block = 32 i x 32 j,
// 4 waves; wave wv owns i_loc [wv*8, wv*8+8), all 32 j (j = j0 + (lane&31)).
// GEMM1: h1T[128][32] = W1c x crossT, C-init = A1[i] (LDS). Epilogue:
// +B1h (hoisted regs), relu, cvt_pk -> P. GEMM2: sigma-W2 x h1T, B-operand =
// own P regs, C-init = b2 (LDS). GEMM3: VALU dot w3 + shfl_xor(32).
// ---------------------------------------------------------------------------
__global__ __launch_bounds__(256, 2) void pair_kernel(
    const unsigned short* __restrict__ src_f16, const unsigned short* __restrict__ dst_f16,
    const float* __restrict__ A1, const unsigned short* __restrict__ B1h,
    const unsigned short* __restrict__ w1c_frag, const unsigned short* __restrict__ w2_frag,
    const float* __restrict__ b2, const float* __restrict__ w3,
    const float* __restrict__ b3, float* __restrict__ out)
{
    __shared__ __align__(16) float sA1[32][128];           // 16 KB
    __shared__ __align__(16) unsigned short sSrc[32][64];  // 4 KB
    __shared__ __align__(16) float sB2[128];
    __shared__ __align__(16) float sW3[64];

    const int tid = threadIdx.x;
    const int wv = tid >> 6;
    const int lane = tid & 63;
    const int hi = lane >> 5, col = lane & 31;
    const int i0 = blockIdx.y * 32, j0 = blockIdx.x * 32;
    const int ibase = wv * 8;

    // ---- cooperative staging (coalesced) ----
    #pragma unroll
    for (int u = 0; u < 4; u++) {
        int idx = u * 256 + tid;              // 0..1023
        int r = idx >> 5, c = (idx & 31) * 4;
        *(f32x4*)&sA1[r][c] = *(const f32x4*)(A1 + (size_t)(i0 + r) * 128 + c);
    }
    {
        int r = tid >> 3, c = (tid & 7) * 8;
        *(uint4*)&sSrc[r][c] = *(const uint4*)(src_f16 + (size_t)(i0 + r) * 64 + c);
    }
    if (tid < 32) *(f32x4*)&sB2[tid * 4] = *(const f32x4*)(b2 + tid * 4);
    else if (tid < 48) *(f32x4*)&sW3[(tid - 32) * 4] = *(const f32x4*)(w3 + (tid - 32) * 4);

    // ---- j-side package: hoisted registers (j = j0 + col, per lane) ----
    const int j = j0 + col;
    half8v dstf[4];
    #pragma unroll
    for (int kt = 0; kt < 4; kt++)
        dstf[kt] = *(const half8v*)(dst_f16 + (size_t)j * 64 + 16 * kt + 8 * hi);
    // b1pk[mt][t] = f16 pair of B1[j] rows (x, x+1), x = ((2t)&3)+8*(t>>1)+4*hi
    unsigned b1pk[4][8];
    #pragma unroll
    for (int mt = 0; mt < 4; mt++)
        #pragma unroll
        for (int t = 0; t < 8; t++) {
            int x = ((2 * t) & 3) + 8 * (t >> 1) + 4 * hi;
            b1pk[mt][t] = *(const unsigned*)(B1h + (size_t)j * 128 + 32 * mt + x);
        }
    const float b3s = b3[0];

    const uint4* gw1 = (const uint4*)w1c_frag;
    const uint4* gw2 = (const uint4*)w2_frag;

    __syncthreads();

    // ---- 8 chunks: one i, 32 pairs each ----
    #pragma unroll 2
    for (int cc = 0; cc < 8; cc++) {
        const int i_loc = ibase + cc;
        const int i = i0 + i_loc;

        // cross features: cf[kt] = src[i] slice * dst[j] slice
        half8v cf[4];
        #pragma unroll
        for (int kt = 0; kt < 4; kt++)
            cf[kt] = (*(const half8v*)&sSrc[i_loc][16 * kt + 8 * hi]) * dstf[kt];

        // C-init = A1[i][row], row = (r&3)+8*(r>>2)+4*hi (+32*mt)
        f32x16 acc1[4];
        #pragma unroll
        for (int mt = 0; mt < 4; mt++)
            #pragma unroll
            for (int s = 0; s < 4; s++) {
                f32x4 v = *(const f32x4*)&sA1[i_loc][32 * mt + 8 * s + 4 * hi];
                acc1[mt][4 * s + 0] = v[0];
                acc1[mt][4 * s + 1] = v[1];
                acc1[mt][4 * s + 2] = v[2];
                acc1[mt][4 * s + 3] = v[3];
            }

        // GEMM1: 16 MFMAs, weight frags loaded near use (kt outer: cf reuse)
        #pragma unroll
        for (int kt = 0; kt < 4; kt++)
            #pragma unroll
            for (int mt = 0; mt < 4; mt++) {
                half8v wf = __builtin_bit_cast(half8v, gw1[(mt * 4 + kt) * 64 + lane]);
                acc1[mt] = __builtin_amdgcn_mfma_f32_32x32x16_f16(wf, cf[kt], acc1[mt], 0, 0, 0);
            }

        // epilogue: +B1, relu, pack f16 -> P[mt][t]
        unsigned P[4][8];
        #pragma unroll
        for (int mt = 0; mt < 4; mt++)
            #pragma unroll
            for (int t = 0; t < 8; t++) {
                half2v p = cvt_pk(acc1[mt][2 * t], acc1[mt][2 * t + 1])
                         + __builtin_bit_cast(half2v, b1pk[mt][t]);
                P[mt][t] = __builtin_bit_cast(unsigned, pkmax0(p));
            }

        // GEMM2: C-init = b2 rows, then 16 MFMAs; B-frag(b) = P[b>>1][4*(b&1)..+3]
        f32x16 acc2[2];
        #pragma unroll
        for (int mt2 = 0; mt2 < 2; mt2++)
            #pragma unroll
            for (int s = 0; s < 4; s++) {
                f32x4 v = *(const f32x4*)&sB2[32 * mt2 + 8 * s + 4 * hi];
                acc2[mt2][4 * s + 0] = v[0];
                acc2[mt2][4 * s + 1] = v[1];
                acc2[mt2][4 * s + 2] = v[2];
                acc2[mt2][4 * s + 3] = v[3];
            }
        #pragma unroll
        for (int b = 0; b < 8; b++) {
            const int mt = b >> 1, h = b & 1;
            uint4 hb = {P[mt][4 * h], P[mt][4 * h + 1], P[mt][4 * h + 2], P[mt][4 * h + 3]};
            half8v hf = __builtin_bit_cast(half8v, hb);
            #pragma unroll
            for (int mt2 = 0; mt2 < 2; mt2++) {
                half8v wf = __builtin_bit_cast(half8v, gw2[(mt2 * 8 + b) * 64 + lane]);
                acc2[mt2] = __builtin_amdgcn_mfma_f32_32x32x16_f16(wf, hf, acc2[mt2], 0, 0, 0);
            }
        }

        // GEMM3 on VALU: part = sum relu(h2[row])*w3[row]; rows split by hi
        float part = 0.0f;
        #pragma unroll
        for (int mt2 = 0; mt2 < 2; mt2++)
            #pragma unroll
            for (int s = 0; s < 4; s++) {
                f32x4 w3t = *(const f32x4*)&sW3[32 * mt2 + 8 * s + 4 * hi];
                #pragma unroll
                for (int q = 0; q < 4; q++)
                    part += fmaxf(acc2[mt2][4 * s + q], 0.0f) * w3t[q];
            }
        part += __shfl_xor(part, 32);   // combine hi halves (same col)
        if (lane < 32)
            out[(size_t)i * 1024 + j0 + col] = part + b3s;
    }
}

// ---------------------------------------------------------------------------
extern "C" void kernel_launch(void* const* d_in, const int* in_sizes, int n_in,
                              void* d_out, int out_size, void* d_ws, size_t ws_size,
                              hipStream_t stream) {
    (void)in_sizes; (void)n_in; (void)out_size; (void)ws_size;
    const float* node   = (const float*)d_in[0];
    const float* w_src  = (const float*)d_in[1];
    const float* b_src  = (const float*)d_in[2];
    const float* g_src  = (const float*)d_in[3];
    const float* be_src = (const float*)d_in[4];
    const float* w_dst  = (const float*)d_in[5];
    const float* b_dst  = (const float*)d_in[6];
    const float* g_dst  = (const float*)d_in[7];
    const float* be_dst = (const float*)d_in[8];
    const float* w1     = (const float*)d_in[9];
    const float* b1     = (const float*)d_in[10];
    const float* w2     = (const float*)d_in[11];
    const float* b2     = (const float*)d_in[12];
    const float* w3     = (const float*)d_in[13];
    const float* b3     = (const float*)d_in[14];

    char* ws = (char*)d_ws;
    unsigned short* src_f16  = (unsigned short*)(ws);
    unsigned short* dst_f16  = (unsigned short*)(ws + 131072);
    float*          A1       = (float*)(ws + 262144);
    unsigned short* B1h      = (unsigned short*)(ws + 786432);
    unsigned short* w1c_frag = (unsigned short*)(ws + 1310720);
    unsigned short* w2_frag  = (unsigned short*)(ws + 1327104);

    hipLaunchKernelGGL(proj_kernel, dim3(512), dim3(256), 0, stream,
                       node, w_src, b_src, g_src, be_src, w_dst, b_dst, g_dst, be_dst,
                       w1, b1, w2, src_f16, dst_f16, A1, B1h,
                       w1c_frag, w2_frag);
    hipLaunchKernelGGL(pair_kernel, dim3(32, 32), dim3(256), 0, stream,
                       src_f16, dst_f16, A1, B1h, w1c_frag, w2_frag, b2, w3, b3,
                       (float*)d_out);
}